// Round 6
// baseline (8086.985 us; speedup 1.0000x reference)
//
#include <hip/hip_runtime.h>
#include <hip/hip_bf16.h>

// SplineConv (degree-1 B-spline, DIM=2, K=5, open), N=100000, E=1600000, 32->32.
// R6: R4/R5 both died from scratch spill (accumulator live across a serial
//     multi-edge loop -> compiler spills; FETCH/WRITE in the GB range, VALU 5%).
//     Proven-clean structure = R2/R3: one edge per 4-lane team, straight-line
//     body (VGPR 28-52, no scratch). R6 keeps that body EXACTLY, feeds it
//     SORTED edges, and combines same-row partials ACROSS THE WAVE with a
//     segmented shfl_down reduction (rows sorted -> runs contiguous; 4 steps,
//     teams are 4 lanes wide). Only the first team of each row-run issues the
//     8 atomicAdds: ~2 distinct rows per 16-edge wave -> atomic dwords
//     51.6M -> ~6.5M, attacking R3's proven limiter (device fp32 atomic
//     throughput ~35 G/s) with zero live state across loops.

#define NN   100000
#define EE   1600000
#define KTOT 25
#define PITCH   40                  // bf16 per (k,i) row: 20 dwords
#define KSTRIDE (32 * PITCH + 8)    // k-stride 644 dwords: spreads bank spans
#define RPITCH  36                  // fp32 pitch for root weight rows

// ws layout (int32 units): counts | offsets | cursor | blksum | sorted
#define WS_COUNTS  0
#define WS_OFFSETS 100000
#define WS_CURSOR  200000
#define WS_BLKSUM  300000
#define WS_SORTED  300128
#define SCAN_NBLK  98               // ceil(100000/1024)

__device__ __forceinline__ float bflo(unsigned d) {
    unsigned u = d << 16;
    return __builtin_bit_cast(float, u);
}
__device__ __forceinline__ float bfhi(unsigned d) {
    unsigned u = d & 0xffff0000u;
    return __builtin_bit_cast(float, u);
}

__global__ void hist_kernel(const int* __restrict__ eidx, int* __restrict__ counts) {
    for (int e = blockIdx.x * blockDim.x + threadIdx.x; e < EE; e += gridDim.x * blockDim.x)
        atomicAdd(&counts[eidx[e]], 1);
}

__global__ __launch_bounds__(1024)
void scan1_kernel(const int* __restrict__ counts, int* __restrict__ offsets,
                  int* __restrict__ blksum) {
    __shared__ int buf[2][1024];
    int tid = threadIdx.x;
    int gid = blockIdx.x * 1024 + tid;
    int v = (gid < NN) ? counts[gid] : 0;
    buf[0][tid] = v;
    __syncthreads();
    int s = 0;
    for (int off = 1; off < 1024; off <<= 1) {
        int t = buf[s][tid];
        if (tid >= off) t += buf[s][tid - off];
        buf[1 - s][tid] = t;
        s ^= 1;
        __syncthreads();
    }
    if (gid < NN) offsets[gid] = buf[s][tid] - v;      // exclusive
    if (tid == 1023) blksum[blockIdx.x] = buf[s][tid]; // block total
}

__global__ void scan2_kernel(int* __restrict__ blksum) {
    if (blockIdx.x == 0 && threadIdx.x == 0) {
        int acc = 0;
        for (int i = 0; i < SCAN_NBLK; ++i) { int v = blksum[i]; blksum[i] = acc; acc += v; }
    }
}

__global__ __launch_bounds__(1024)
void scan3_kernel(int* __restrict__ offsets, const int* __restrict__ blksum,
                  int* __restrict__ cursor) {
    int gid = blockIdx.x * 1024 + threadIdx.x;
    if (gid < NN) {
        int o = offsets[gid] + blksum[blockIdx.x];
        offsets[gid] = o;
        cursor[gid] = o;
    }
}

__global__ void scatter_kernel(const int* __restrict__ eidx, int* __restrict__ cursor,
                               int* __restrict__ sorted) {
    for (int e = blockIdx.x * blockDim.x + threadIdx.x; e < EE; e += gridDim.x * blockDim.x) {
        int pos = atomicAdd(&cursor[eidx[e]], 1);
        sorted[pos] = e;
    }
}

__global__ __launch_bounds__(512, 4)
void run_kernel(const float* __restrict__ x,
                const int* __restrict__ eidx,
                const float* __restrict__ pseudo,
                const float* __restrict__ weight,
                const int* __restrict__ sorted,
                float* __restrict__ acc)     // d_out as accumulator, pre-zeroed
{
    __shared__ __hip_bfloat16 wl[KTOT * KSTRIDE];   // 64400 B

    for (int idx = threadIdx.x; idx < KTOT * 1024; idx += 512) {
        int k = idx >> 10;
        int r = idx & 1023;
        wl[k * KSTRIDE + (r >> 5) * PITCH + (r & 31)] = __float2bfloat16(weight[idx]);
    }
    __syncthreads();

    const int sub  = threadIdx.x & 3;   // quarter of output channels
    const int og   = sub * 8;
    const int lane = threadIdx.x & 63;

    for (int base = blockIdx.x * 128; base < EE; base += gridDim.x * 128) {
        int e = base + (threadIdx.x >> 2);
        int row = -1;
        float y[8] = {0, 0, 0, 0, 0, 0, 0, 0};

        if (e < EE) {
            e = sorted[e];
            row = eidx[e];
            int col = eidx[EE + e];

            // degree-1 spline basis, scale = K-1 = 4 (open)
            const float2 ps = *(const float2*)(pseudo + 2 * e);
            float p0 = ps.x * 4.0f;
            float p1 = ps.y * 4.0f;
            float l0f = floorf(p0), l1f = floorf(p1);
            float f0 = p0 - l0f, f1 = p1 - l1f;
            int l0 = (int)l0f, l1 = (int)l1f;
            int i0a = min(max(l0, 0), 4),     i0b = min(max(l0 + 1, 0), 4);
            int i1a = min(max(l1, 0), 4),     i1b = min(max(l1 + 1, 0), 4);
            float b0 = (1.0f - f0) * (1.0f - f1); int k0 = i0a + 5 * i1a;
            float b1 = (1.0f - f0) * f1;          int k1 = i0a + 5 * i1b;
            float b2 = f0 * (1.0f - f1);          int k2 = i0b + 5 * i1a;
            float b3 = f0 * f1;                   int k3 = i0b + 5 * i1b;

            const float4* xp = (const float4*)(x + col * 32);
            const __hip_bfloat16* pa = &wl[k0 * KSTRIDE + og];
            const __hip_bfloat16* pb = &wl[k1 * KSTRIDE + og];
            const __hip_bfloat16* pc = &wl[k2 * KSTRIDE + og];
            const __hip_bfloat16* pd = &wl[k3 * KSTRIDE + og];

            #pragma unroll
            for (int q = 0; q < 8; ++q) {
                float4 v = xp[q];
                float xq[4] = {v.x, v.y, v.z, v.w};
                #pragma unroll
                for (int r = 0; r < 4; ++r) {
                    int i = 4 * q + r;
                    float xi = xq[r];
                    uint4 wA = *(const uint4*)(pa + i * PITCH);
                    uint4 wB = *(const uint4*)(pb + i * PITCH);
                    uint4 wC = *(const uint4*)(pc + i * PITCH);
                    uint4 wD = *(const uint4*)(pd + i * PITCH);
                    const unsigned* A = (const unsigned*)&wA;
                    const unsigned* B = (const unsigned*)&wB;
                    const unsigned* C = (const unsigned*)&wC;
                    const unsigned* D = (const unsigned*)&wD;
                    #pragma unroll
                    for (int h = 0; h < 4; ++h) {
                        float wsL = b0 * bflo(A[h]) + b1 * bflo(B[h])
                                  + b2 * bflo(C[h]) + b3 * bflo(D[h]);
                        float wsH = b0 * bfhi(A[h]) + b1 * bfhi(B[h])
                                  + b2 * bfhi(C[h]) + b3 * bfhi(D[h]);
                        y[2 * h]     = fmaf(xi, wsL, y[2 * h]);
                        y[2 * h + 1] = fmaf(xi, wsH, y[2 * h + 1]);
                    }
                }
            }
        }

        // Segmented reduction across the wave's 16 teams (rows sorted ->
        // equal-row teams are contiguous). After this, the FIRST team of each
        // row-run holds the run's full sum.
        #pragma unroll
        for (int d = 4; d <= 32; d <<= 1) {
            int r_in = __shfl_down(row, d, 64);
            bool merge = (lane + d < 64) && (r_in == row);
            #pragma unroll
            for (int c = 0; c < 8; ++c) {
                float t = __shfl_down(y[c], d, 64);
                y[c] += merge ? t : 0.0f;
            }
        }
        int r_prev = __shfl_up(row, 4, 64);
        bool flush = (row >= 0) && ((lane < 4) || (r_prev != row));
        if (flush) {
            float* dst = acc + row * 32 + og;
            #pragma unroll
            for (int c = 0; c < 8; ++c) atomicAdd(dst + c, y[c]);
        }
    }
}

__global__ __launch_bounds__(256)
void finalize_kernel(const float* __restrict__ x,
                     const float* __restrict__ rootw,  // [32*32] i-major
                     const float* __restrict__ bias,   // [32]
                     const int* __restrict__ counts,   // [N] degrees
                     float* __restrict__ out)          // [N*32] in/out
{
    __shared__ float rw[32 * RPITCH];
    __shared__ float bs[32];
    for (int idx = threadIdx.x; idx < 1024; idx += 256)
        rw[(idx >> 5) * RPITCH + (idx & 31)] = rootw[idx];
    if (threadIdx.x < 32) bs[threadIdx.x] = bias[threadIdx.x];
    __syncthreads();

    int tid = blockIdx.x * 256 + threadIdx.x;
    int n = tid >> 5, o = tid & 31;
    if (n >= NN) return;

    float xv = x[n * 32 + o];
    int gb = (threadIdx.x & 63) & ~31;
    float v = 0.0f;
    #pragma unroll
    for (int i = 0; i < 32; ++i) {
        float xi = __shfl(xv, gb + i, 64);
        v = fmaf(xi, rw[i * RPITCH + o], v);
    }
    float d = fmaxf((float)counts[n], 1.0f);
    int idx = n * 32 + o;
    out[idx] = out[idx] / d + v + bs[o];
}

extern "C" void kernel_launch(void* const* d_in, const int* in_sizes, int n_in,
                              void* d_out, int out_size, void* d_ws, size_t ws_size,
                              hipStream_t stream) {
    const float* x      = (const float*)d_in[0];
    const int*   eidx   = (const int*)d_in[1];
    const float* pseudo = (const float*)d_in[2];
    const float* weight = (const float*)d_in[3];
    const float* rootw  = (const float*)d_in[4];
    const float* bias   = (const float*)d_in[5];
    float* out = (float*)d_out;

    int* ws      = (int*)d_ws;
    int* counts  = ws + WS_COUNTS;
    int* offsets = ws + WS_OFFSETS;
    int* cursor  = ws + WS_CURSOR;
    int* blksum  = ws + WS_BLKSUM;
    int* sorted  = ws + WS_SORTED;

    hipMemsetAsync(counts, 0, (size_t)NN * sizeof(int), stream);
    hipMemsetAsync(out, 0, (size_t)NN * 32 * sizeof(float), stream);

    hist_kernel   <<<2048, 256, 0, stream>>>(eidx, counts);
    scan1_kernel  <<<SCAN_NBLK, 1024, 0, stream>>>(counts, offsets, blksum);
    scan2_kernel  <<<1, 64, 0, stream>>>(blksum);
    scan3_kernel  <<<SCAN_NBLK, 1024, 0, stream>>>(offsets, blksum, cursor);
    scatter_kernel<<<2048, 256, 0, stream>>>(eidx, cursor, sorted);

    run_kernel<<<1024, 512, 0, stream>>>(x, eidx, pseudo, weight, sorted, out);

    finalize_kernel<<<(NN * 32 + 255) / 256, 256, 0, stream>>>(
        x, rootw, bias, counts, out);
}

// Round 7
// 884.781 us; speedup vs baseline: 9.1401x; 9.1401x over previous
//
#include <hip/hip_runtime.h>
#include <hip/hip_bf16.h>

// SplineConv (degree-1 B-spline, DIM=2, K=5, open), N=100000, E=1600000, 32->32.
// R7: three rounds (R4 serial-node, R5 serial-run, R6 shfl-reduce) all spilled
//     the accumulator to scratch (FETCH/WRITE in GBs, VALU ~4%). The only
//     spill-free structure is R2/R3's straight-line per-edge body with results
//     consumed immediately. R7 keeps that body verbatim but consumes y[8] into
//     an LDS row tile (ds_add_f32, pitch 33): block b owns rows [64b,64b+64)
//     of the SORTED edge list, so after a barrier the tile flushes with plain
//     coalesced stores -- ZERO fp32 global atomics (R3's proven 35 G/s
//     saturated limiter). /deg + x@root + bias fused into the flush; finalize
//     kernel and out-memset deleted. Teams take contiguous ~8-edge chunks so
//     same-wave teams sit on different rows (avoids same-address LDS
//     serialization and spreads tile banks).

#define NN   100000
#define EE   1600000
#define KTOT 25
#define PITCH   40                  // bf16 per (k,i) row: 20 dwords
#define KSTRIDE (32 * PITCH + 8)    // k-stride 644 dwords: spreads bank spans
#define RPITCH  36                  // fp32 pitch for root weight rows
#define ROWS_PB 64                  // rows owned per block
#define TPITCH  33                  // tile pitch (dwords): breaks bank degeneracy
#define NBLK    ((NN + ROWS_PB - 1) / ROWS_PB)   // 1563

// ws layout (int32 units): counts | offsets | cursor | blksum | sorted
#define WS_COUNTS  0
#define WS_OFFSETS 100000
#define WS_CURSOR  200000
#define WS_BLKSUM  300000
#define WS_SORTED  300128
#define SCAN_NBLK  98               // ceil(100000/1024)

__device__ __forceinline__ float bflo(unsigned d) {
    unsigned u = d << 16;
    return __builtin_bit_cast(float, u);
}
__device__ __forceinline__ float bfhi(unsigned d) {
    unsigned u = d & 0xffff0000u;
    return __builtin_bit_cast(float, u);
}

__global__ void hist_kernel(const int* __restrict__ eidx, int* __restrict__ counts) {
    for (int e = blockIdx.x * blockDim.x + threadIdx.x; e < EE; e += gridDim.x * blockDim.x)
        atomicAdd(&counts[eidx[e]], 1);
}

__global__ __launch_bounds__(1024)
void scan1_kernel(const int* __restrict__ counts, int* __restrict__ offsets,
                  int* __restrict__ blksum) {
    __shared__ int buf[2][1024];
    int tid = threadIdx.x;
    int gid = blockIdx.x * 1024 + tid;
    int v = (gid < NN) ? counts[gid] : 0;
    buf[0][tid] = v;
    __syncthreads();
    int s = 0;
    for (int off = 1; off < 1024; off <<= 1) {
        int t = buf[s][tid];
        if (tid >= off) t += buf[s][tid - off];
        buf[1 - s][tid] = t;
        s ^= 1;
        __syncthreads();
    }
    if (gid < NN) offsets[gid] = buf[s][tid] - v;      // exclusive
    if (tid == 1023) blksum[blockIdx.x] = buf[s][tid]; // block total
}

__global__ void scan2_kernel(int* __restrict__ blksum) {
    if (blockIdx.x == 0 && threadIdx.x == 0) {
        int acc = 0;
        for (int i = 0; i < SCAN_NBLK; ++i) { int v = blksum[i]; blksum[i] = acc; acc += v; }
    }
}

__global__ __launch_bounds__(1024)
void scan3_kernel(int* __restrict__ offsets, const int* __restrict__ blksum,
                  int* __restrict__ cursor) {
    int gid = blockIdx.x * 1024 + threadIdx.x;
    if (gid < NN) {
        int o = offsets[gid] + blksum[blockIdx.x];
        offsets[gid] = o;
        cursor[gid] = o;
    }
}

__global__ void scatter_kernel(const int* __restrict__ eidx, int* __restrict__ cursor,
                               int* __restrict__ sorted) {
    for (int e = blockIdx.x * blockDim.x + threadIdx.x; e < EE; e += gridDim.x * blockDim.x) {
        int pos = atomicAdd(&cursor[eidx[e]], 1);
        sorted[pos] = e;
    }
}

__global__ __launch_bounds__(512, 4)
void block_kernel(const float* __restrict__ x,
                  const int* __restrict__ eidx,
                  const float* __restrict__ pseudo,
                  const float* __restrict__ weight,
                  const float* __restrict__ rootw,
                  const float* __restrict__ bias,
                  const int* __restrict__ offsets,
                  const int* __restrict__ cursor,   // post-scatter: row end offsets
                  const int* __restrict__ counts,   // row degrees
                  const int* __restrict__ sorted,
                  float* __restrict__ out)
{
    __shared__ __hip_bfloat16 wl[KTOT * KSTRIDE];   // 64400 B
    __shared__ float tile[ROWS_PB * TPITCH];        //  8448 B
    __shared__ float rw[32 * RPITCH];               //  4608 B
    __shared__ float bs[32];

    for (int idx = threadIdx.x; idx < KTOT * 1024; idx += 512) {
        int k = idx >> 10;
        int r = idx & 1023;
        wl[k * KSTRIDE + (r >> 5) * PITCH + (r & 31)] = __float2bfloat16(weight[idx]);
    }
    for (int idx = threadIdx.x; idx < 1024; idx += 512)
        rw[(idx >> 5) * RPITCH + (idx & 31)] = rootw[idx];
    if (threadIdx.x < 32) bs[threadIdx.x] = bias[threadIdx.x];
    for (int idx = threadIdx.x; idx < ROWS_PB * TPITCH; idx += 512)
        tile[idx] = 0.0f;
    __syncthreads();

    const int row0  = blockIdx.x * ROWS_PB;
    const int rlast = min(row0 + ROWS_PB, NN) - 1;
    const int start = offsets[row0];
    const int end   = cursor[rlast];              // offsets[rlast] + counts[rlast]
    const int cnt   = end - start;
    const int chunk = (cnt + 127) >> 7;           // edges per team (128 teams)

    const int t   = threadIdx.x >> 2;             // team 0..127
    const int sub = threadIdx.x & 3;
    const int og  = sub * 8;

    const int ts = start + t * chunk;
    const int te = min(ts + chunk, end);

    for (int e0 = ts; e0 < te; ++e0) {
        int e = sorted[e0];
        int row = eidx[e];
        int col = eidx[EE + e];

        // degree-1 spline basis, scale = K-1 = 4 (open)
        const float2 ps = *(const float2*)(pseudo + 2 * e);
        float p0 = ps.x * 4.0f;
        float p1 = ps.y * 4.0f;
        float l0f = floorf(p0), l1f = floorf(p1);
        float f0 = p0 - l0f, f1 = p1 - l1f;
        int l0 = (int)l0f, l1 = (int)l1f;
        int i0a = min(max(l0, 0), 4),     i0b = min(max(l0 + 1, 0), 4);
        int i1a = min(max(l1, 0), 4),     i1b = min(max(l1 + 1, 0), 4);
        float b0 = (1.0f - f0) * (1.0f - f1); int k0 = i0a + 5 * i1a;
        float b1 = (1.0f - f0) * f1;          int k1 = i0a + 5 * i1b;
        float b2 = f0 * (1.0f - f1);          int k2 = i0b + 5 * i1a;
        float b3 = f0 * f1;                   int k3 = i0b + 5 * i1b;

        const float4* xp = (const float4*)(x + col * 32);
        const __hip_bfloat16* pa = &wl[k0 * KSTRIDE + og];
        const __hip_bfloat16* pb = &wl[k1 * KSTRIDE + og];
        const __hip_bfloat16* pc = &wl[k2 * KSTRIDE + og];
        const __hip_bfloat16* pd = &wl[k3 * KSTRIDE + og];

        float y[8] = {0, 0, 0, 0, 0, 0, 0, 0};

        #pragma unroll
        for (int q = 0; q < 8; ++q) {
            float4 v = xp[q];
            float xq[4] = {v.x, v.y, v.z, v.w};
            #pragma unroll
            for (int r = 0; r < 4; ++r) {
                int i = 4 * q + r;
                float xi = xq[r];
                uint4 wA = *(const uint4*)(pa + i * PITCH);
                uint4 wB = *(const uint4*)(pb + i * PITCH);
                uint4 wC = *(const uint4*)(pc + i * PITCH);
                uint4 wD = *(const uint4*)(pd + i * PITCH);
                const unsigned* A = (const unsigned*)&wA;
                const unsigned* B = (const unsigned*)&wB;
                const unsigned* C = (const unsigned*)&wC;
                const unsigned* D = (const unsigned*)&wD;
                #pragma unroll
                for (int h = 0; h < 4; ++h) {
                    float wsL = b0 * bflo(A[h]) + b1 * bflo(B[h])
                              + b2 * bflo(C[h]) + b3 * bflo(D[h]);
                    float wsH = b0 * bfhi(A[h]) + b1 * bfhi(B[h])
                              + b2 * bfhi(C[h]) + b3 * bfhi(D[h]);
                    y[2 * h]     = fmaf(xi, wsL, y[2 * h]);
                    y[2 * h + 1] = fmaf(xi, wsH, y[2 * h + 1]);
                }
            }
        }

        // Consume y immediately into the LDS row tile (no live state across edges).
        float* tp = &tile[(row - row0) * TPITCH + og];
        #pragma unroll
        for (int c = 0; c < 8; ++c) atomicAdd(tp + c, y[c]);
    }

    __syncthreads();

    // Flush: plain coalesced stores, fused with /deg + x@root_weight + bias.
    for (int d = threadIdx.x; d < ROWS_PB * 32; d += 512) {
        int r  = d >> 5;
        int ch = d & 31;
        int row = row0 + r;
        if (row < NN) {
            float s  = tile[r * TPITCH + ch];
            float dg = fmaxf((float)counts[row], 1.0f);
            float v  = 0.0f;
            #pragma unroll
            for (int i = 0; i < 32; ++i)
                v = fmaf(x[row * 32 + i], rw[i * RPITCH + ch], v);
            out[row * 32 + ch] = s / dg + v + bs[ch];
        }
    }
}

extern "C" void kernel_launch(void* const* d_in, const int* in_sizes, int n_in,
                              void* d_out, int out_size, void* d_ws, size_t ws_size,
                              hipStream_t stream) {
    const float* x      = (const float*)d_in[0];
    const int*   eidx   = (const int*)d_in[1];
    const float* pseudo = (const float*)d_in[2];
    const float* weight = (const float*)d_in[3];
    const float* rootw  = (const float*)d_in[4];
    const float* bias   = (const float*)d_in[5];
    float* out = (float*)d_out;

    int* ws      = (int*)d_ws;
    int* counts  = ws + WS_COUNTS;
    int* offsets = ws + WS_OFFSETS;
    int* cursor  = ws + WS_CURSOR;
    int* blksum  = ws + WS_BLKSUM;
    int* sorted  = ws + WS_SORTED;

    hipMemsetAsync(counts, 0, (size_t)NN * sizeof(int), stream);

    hist_kernel   <<<2048, 256, 0, stream>>>(eidx, counts);
    scan1_kernel  <<<SCAN_NBLK, 1024, 0, stream>>>(counts, offsets, blksum);
    scan2_kernel  <<<1, 64, 0, stream>>>(blksum);
    scan3_kernel  <<<SCAN_NBLK, 1024, 0, stream>>>(offsets, blksum, cursor);
    scatter_kernel<<<2048, 256, 0, stream>>>(eidx, cursor, sorted);

    block_kernel<<<NBLK, 512, 0, stream>>>(
        x, eidx, pseudo, weight, rootw, bias, offsets, cursor, counts, sorted, out);
}